// Round 1
// baseline (2063.430 us; speedup 1.0000x reference)
//
#include <hip/hip_runtime.h>
#include <hip/hip_bf16.h>
#include <cstdint>

// ---------------------------------------------------------------------------
// SiameseGNN: GCNx2 on big graph (N1=102400, E1=1.64M) and small graph
// (N2=199), partial cdist, SortAggregation top-50 per graph, MLP head.
// All f32. Key algorithmic save: never materialize the full [N1 x N2] dist
// matrix; only the last column (selection key) + rows of selected nodes.
// ---------------------------------------------------------------------------

#define DEV_INLINE __device__ __forceinline__

// ---------------- init: deg1=1.0 (self loop), cnt=0, cur=0 -----------------
__global__ void init1_kernel(float* deg, int* cnt, int* cur, int n) {
    int i = blockIdx.x * 256 + threadIdx.x;
    if (i < n) { deg[i] = 1.0f; cnt[i] = 0; cur[i] = 0; }
}

// ---------------- histogram: deg += ew, cnt += 1 per dst -------------------
__global__ void hist_kernel(const int* __restrict__ dst, const float* __restrict__ ew,
                            float* deg, int* cnt, int E) {
    int e = blockIdx.x * 256 + threadIdx.x;
    if (e < E) {
        int d = dst[e];
        atomicAdd(&deg[d], ew[e]);
        atomicAdd(&cnt[d], 1);
    }
}

// ---------------- dinv = rsqrt(deg) in place -------------------------------
__global__ void rsqrt_kernel(float* deg, int n) {
    int i = blockIdx.x * 256 + threadIdx.x;
    if (i < n) deg[i] = rsqrtf(deg[i]);
}

// ---------------- exclusive scan of cnt -> off (single block, 1024 thr) ----
__global__ __launch_bounds__(1024) void scan_kernel(const int* __restrict__ cnt,
                                                    int* __restrict__ off, int n) {
    __shared__ int wsum[16], woff[16];
    __shared__ int carry_s, tot_s;
    int t = threadIdx.x, lane = t & 63, wid = t >> 6;
    if (t == 0) carry_s = 0;
    __syncthreads();
    for (int base = 0; base < n; base += 1024) {
        int i = base + t;
        int v = (i < n) ? cnt[i] : 0;
        int s = v;
        for (int d = 1; d < 64; d <<= 1) { int u = __shfl_up(s, d); if (lane >= d) s += u; }
        if (lane == 63) wsum[wid] = s;
        __syncthreads();
        if (t == 0) {
            int run = 0;
            for (int w2 = 0; w2 < 16; w2++) { int u = wsum[w2]; woff[w2] = run; run += u; }
            tot_s = run;
        }
        __syncthreads();
        if (i < n) off[i] = carry_s + woff[wid] + s - v;   // exclusive
        __syncthreads();
        if (t == 0) carry_s += tot_s;
        __syncthreads();
    }
    if (threadIdx.x == 0) off[n] = carry_s;
}

// ---------------- CSR edge placement (order within bucket arbitrary) -------
__global__ void csr_kernel(const int* __restrict__ dst, const int* __restrict__ off,
                           int* cur, int* __restrict__ csre, int E) {
    int e = blockIdx.x * 256 + threadIdx.x;
    if (e < E) {
        int d = dst[e];
        int pos = off[d] + atomicAdd(&cur[d], 1);
        csre[pos] = e;
    }
}

// ---------------- GEMM: [nrows,128] @ [128,NCOL] -> [nrows,NCOL] -----------
// 64-row tile per block, split-K into 2 LDS-staged halves. f32 vector FMA.
template <int NCOL>
__global__ __launch_bounds__(256) void gemm_kernel(const float* __restrict__ x,
                                                   const float* __restrict__ w,
                                                   float* __restrict__ out, int nrows) {
    constexpr int TX = NCOL / 8;       // 16 or 8
    constexpr int TY = 256 / TX;       // 16 or 32
    constexpr int AR = 64 / TY;        // 4 or 2 rows per thread
    __shared__ float ws[64 * NCOL];
    __shared__ float xs[64 * 68];      // pad 64->68 for bank spread
    int t = threadIdx.x;
    size_t r0 = (size_t)blockIdx.x * 64;
    int tx = t % TX, ty = t / TX;
    float acc[AR][8];
#pragma unroll
    for (int i = 0; i < AR; i++)
#pragma unroll
        for (int j = 0; j < 8; j++) acc[i][j] = 0.f;

    for (int half = 0; half < 2; half++) {
        __syncthreads();
        for (int f = t; f < 64 * NCOL / 4; f += 256)
            ((float4*)ws)[f] = ((const float4*)(w + half * 64 * NCOL))[f];
        for (int f = t; f < 64 * 16; f += 256) {
            int row = f >> 4, c4 = f & 15;
            float4 v = *((const float4*)(x + (r0 + row) * 128 + half * 64 + c4 * 4));
            *((float4*)(xs + row * 68 + c4 * 4)) = v;
        }
        __syncthreads();
        for (int k = 0; k < 64; k++) {
            float4 b0 = *((const float4*)(ws + k * NCOL + tx * 8));
            float4 b1 = *((const float4*)(ws + k * NCOL + tx * 8 + 4));
            float bb[8] = {b0.x, b0.y, b0.z, b0.w, b1.x, b1.y, b1.z, b1.w};
#pragma unroll
            for (int i = 0; i < AR; i++) {
                float a = xs[(ty * AR + i) * 68 + k];
#pragma unroll
                for (int j = 0; j < 8; j++) acc[i][j] = fmaf(a, bb[j], acc[i][j]);
            }
        }
    }
#pragma unroll
    for (int i = 0; i < AR; i++) {
        size_t row = r0 + ty * AR + i;
        float4 v0 = {acc[i][0], acc[i][1], acc[i][2], acc[i][3]};
        float4 v1 = {acc[i][4], acc[i][5], acc[i][6], acc[i][7]};
        *((float4*)(out + row * NCOL + tx * 8)) = v0;
        *((float4*)(out + row * NCOL + tx * 8 + 4)) = v1;
    }
}

// ---------------- CSR aggregation: out = relu(Ahat z + b) ------------------
// one wave per node; edge metadata loaded lane-parallel, shfl-broadcast.
template <int C>
__global__ __launch_bounds__(256) void agg_kernel(const float* __restrict__ z,
                                                  const int* __restrict__ csre,
                                                  const int* __restrict__ off,
                                                  const int* __restrict__ src,
                                                  const float* __restrict__ ew,
                                                  const float* __restrict__ dinv,
                                                  const float* __restrict__ bias,
                                                  float* __restrict__ out, int n) {
    constexpr int CPL = C / 64;   // 2 or 1 channels per lane
    int wid = threadIdx.x >> 6;
    int lane = threadIdx.x & 63;
    int d = blockIdx.x * 4 + wid;
    if (d >= n) return;
    float dv = dinv[d];
    float acc0, acc1 = 0.f;
    if constexpr (CPL == 2) {
        float2 zv = *((const float2*)(z + (size_t)d * C + lane * 2));
        acc0 = dv * zv.x; acc1 = dv * zv.y;
    } else {
        acc0 = dv * z[(size_t)d * C + lane];
    }
    int o0 = off[d], o1e = off[d + 1];
    for (int base = o0; base < o1e; base += 64) {
        int m = min(64, o1e - base);
        int s = 0; float w = 0.f;
        if (lane < m) {
            int e = csre[base + lane];
            s = src[e];
            w = ew[e] * dinv[s];
        }
        for (int j = 0; j < m; j++) {
            int sj = __shfl(s, j);
            float wj = __shfl(w, j);
            if constexpr (CPL == 2) {
                float2 zv = *((const float2*)(z + (size_t)sj * C + lane * 2));
                acc0 = fmaf(wj, zv.x, acc0);
                acc1 = fmaf(wj, zv.y, acc1);
            } else {
                acc0 = fmaf(wj, z[(size_t)sj * C + lane], acc0);
            }
        }
    }
    if constexpr (CPL == 2) {
        int c = lane * 2;
        out[(size_t)d * C + c]     = fmaxf(dv * acc0 + bias[c], 0.f);
        out[(size_t)d * C + c + 1] = fmaxf(dv * acc1 + bias[c + 1], 0.f);
    } else {
        out[(size_t)d * C + lane] = fmaxf(dv * acc0 + bias[lane], 0.f);
    }
}

// ---------------- graph2: deg->dinv + zero the scatter buffers -------------
__global__ void g2_prep(const int* __restrict__ ei2, const float* __restrict__ ew2,
                        float* dinv2, float* a2a, float* a2b, int E2, int N2) {
    __shared__ float degl[256];
    int t = threadIdx.x;
    degl[t] = 1.0f;
    __syncthreads();
    for (int e = t; e < E2; e += 256) atomicAdd(&degl[ei2[E2 + e]], ew2[e]);
    __syncthreads();
    if (t < N2) dinv2[t] = rsqrtf(degl[t]);
    for (int i = t; i < N2 * 128; i += 256) a2a[i] = 0.f;
    for (int i = t; i < N2 * 64; i += 256) a2b[i] = 0.f;
}

// ---------------- graph2 row-GEMM: block per row ---------------------------
template <int NCOL>
__global__ void g2_gemm(const float* __restrict__ x, const float* __restrict__ w,
                        float* __restrict__ z, int N2) {
    __shared__ float xr[128];
    int row = blockIdx.x, t = threadIdx.x;
    for (int k = t; k < 128; k += NCOL) xr[k] = x[row * 128 + k];
    __syncthreads();
    float acc = 0.f;
    for (int k = 0; k < 128; k++) acc = fmaf(xr[k], w[k * NCOL + t], acc);
    z[row * NCOL + t] = acc;
}

// ---------------- graph2 scatter-atomic aggregation ------------------------
template <int C>
__global__ void g2_scatter(const float* __restrict__ z, const int* __restrict__ ei2,
                           const float* __restrict__ ew2, const float* __restrict__ dinv2,
                           float* a2, int E2) {
    constexpr int CPL = C / 64;
    int wid = threadIdx.x >> 6, lane = threadIdx.x & 63;
    int e = blockIdx.x * 4 + wid;
    if (e >= E2) return;
    int s = ei2[e], d = ei2[E2 + e];
    float nm = dinv2[s] * ew2[e] * dinv2[d];
#pragma unroll
    for (int q = 0; q < CPL; q++) {
        int c = lane * CPL + q;
        atomicAdd(&a2[d * C + c], nm * z[s * C + c]);
    }
}

template <int C>
__global__ void g2_fin(const float* __restrict__ a2, const float* __restrict__ z,
                       const float* __restrict__ dinv2, const float* __restrict__ bias,
                       float* __restrict__ out, int N2) {
    int i = blockIdx.x * 256 + threadIdx.x;
    if (i >= N2 * C) return;
    int n = i / C, c = i % C;
    float dv = dinv2[n];
    out[i] = fmaxf(a2[i] + dv * dv * z[i] + bias[c], 0.f);
}

// ---------------- s2[j] = |o2[j]|^2 ----------------------------------------
__global__ void s2_kernel(const float* __restrict__ o2, float* s2, int N2) {
    int wid = threadIdx.x >> 6, lane = threadIdx.x & 63;
    int j = blockIdx.x * 4 + wid;
    if (j >= N2) return;
    float v = o2[j * 64 + lane];
    float ss = v * v;
    for (int d = 32; d >= 1; d >>= 1) ss += __shfl_xor(ss, d);
    if (lane == 0) s2[j] = ss;
}

// ---------------- dlast[i] = dist(o1[i], o2[N2-1]) -------------------------
__global__ void dlast_kernel(const float* __restrict__ o1, const float* __restrict__ o2,
                             const float* __restrict__ s2, float* __restrict__ dlast,
                             int n, int N2) {
    int wid = threadIdx.x >> 6, lane = threadIdx.x & 63;
    int i = blockIdx.x * 4 + wid;
    if (i >= n) return;
    float a = o1[(size_t)i * 64 + lane];
    float b = o2[(size_t)(N2 - 1) * 64 + lane];
    float aa = a * a, ab = a * b;
    for (int d = 32; d >= 1; d >>= 1) { aa += __shfl_xor(aa, d); ab += __shfl_xor(ab, d); }
    if (lane == 0) {
        float d2 = aa + s2[N2 - 1] - 2.f * ab;
        dlast[i] = sqrtf(fmaxf(d2, 0.f) + 1e-12f);
    }
}

// ---------------- top-K per graph (iterative argmax, stable ties) ----------
__global__ __launch_bounds__(256) void topk_kernel(const float* __restrict__ dlast,
                                                   int* __restrict__ topidx,
                                                   int NPG, int K) {
    __shared__ unsigned long long keys[1600];
    __shared__ unsigned long long red[256];
    int g = blockIdx.x, t = threadIdx.x;
    for (int r = t; r < NPG; r += 256) {
        unsigned vb = __float_as_uint(dlast[(size_t)g * NPG + r]);  // dist > 0
        keys[r] = ((unsigned long long)vb << 32) | (unsigned)(NPG - 1 - r);
    }
    __syncthreads();
    for (int it = 0; it < K; it++) {
        unsigned long long m = 0ull;
        for (int r = t; r < NPG; r += 256) { unsigned long long k = keys[r]; if (k > m) m = k; }
        red[t] = m;
        __syncthreads();
        for (int s = 128; s >= 1; s >>= 1) {
            if (t < s) { if (red[t + s] > red[t]) red[t] = red[t + s]; }
            __syncthreads();
        }
        int rbest = NPG - 1 - (int)(red[0] & 0xffffffffull);
        if (t == 0) { topidx[g * K + it] = rbest; keys[rbest] = 0ull; }
        __syncthreads();
    }
}

// ---------------- pooled rows: dist(o1[sel], o2[j]) for j<N2 ---------------
__global__ void pooled_kernel(const float* __restrict__ o1, const float* __restrict__ o2,
                              const float* __restrict__ s2, const int* __restrict__ topidx,
                              float* __restrict__ pooled, int NPG, int K, int N2) {
    __shared__ float o1s[64];
    __shared__ float s1sh;
    int g = blockIdx.x / K, kk = blockIdx.x % K;
    int t = threadIdx.x;
    int r = topidx[g * K + kk];
    size_t node = (size_t)g * NPG + r;
    if (t < 64) o1s[t] = o1[node * 64 + t];
    __syncthreads();
    if (t < 64) {
        float v = o1s[t]; float ss = v * v;
        for (int d = 32; d >= 1; d >>= 1) ss += __shfl_xor(ss, d);
        if (t == 0) s1sh = ss;
    }
    __syncthreads();
    if (t < N2) {
        float dot = 0.f;
#pragma unroll 8
        for (int k2 = 0; k2 < 64; k2++) dot = fmaf(o1s[k2], o2[t * 64 + k2], dot);
        float d2 = s1sh + s2[t] - 2.f * dot;
        pooled[(size_t)blockIdx.x * N2 + t] = sqrtf(fmaxf(d2, 0.f) + 1e-12f);
    }
}

// ---------------- MLP head: fc1+LN+relu+fc2+LN+relu+fc3+sigmoid ------------
__global__ __launch_bounds__(256) void head_kernel(
    const float* __restrict__ pooled, const float* __restrict__ fc1W,
    const float* __restrict__ fc1b, const float* __restrict__ ln1g,
    const float* __restrict__ ln1b, const float* __restrict__ fc2W,
    const float* __restrict__ fc2b, const float* __restrict__ ln2g,
    const float* __restrict__ ln2b, const float* __restrict__ fc3W,
    const float* __restrict__ fc3b, float* __restrict__ out, int PK) {
    __shared__ float p[9950];
    __shared__ float red[256];
    __shared__ float h1[128];
    __shared__ float h2[64];
    int b = blockIdx.x, t = threadIdx.x;
    for (int i = t; i < PK; i += 256) p[i] = pooled[(size_t)b * PK + i];
    __syncthreads();
    // fc1: split rows across 2 halves of the block
    int c = t & 127, half = t >> 7;
    int rbeg = half * (PK / 2), rend = rbeg + PK / 2;
    float acc = 0.f;
    for (int r = rbeg; r < rend; r++) acc = fmaf(p[r], fc1W[(size_t)r * 128 + c], acc);
    red[t] = acc;
    __syncthreads();
    if (t < 128) h1[t] = red[t] + red[t + 128] + fc1b[t];
    __syncthreads();
    // LN1 (mean)
    red[t] = (t < 128) ? h1[t] : 0.f;
    __syncthreads();
    for (int s = 128; s >= 1; s >>= 1) { if (t < s) red[t] += red[t + s]; __syncthreads(); }
    float mean1 = red[0] / 128.f;
    __syncthreads();
    float dv1 = (t < 128) ? (h1[t] - mean1) : 0.f;
    red[t] = dv1 * dv1;
    __syncthreads();
    for (int s = 128; s >= 1; s >>= 1) { if (t < s) red[t] += red[t + s]; __syncthreads(); }
    float var1 = red[0] / 128.f;
    __syncthreads();
    if (t < 128) {
        float y = (h1[t] - mean1) * rsqrtf(var1 + 1e-5f) * ln1g[t] + ln1b[t];
        h1[t] = fmaxf(y, 0.f);
    }
    __syncthreads();
    // fc2
    if (t < 64) {
        float a2v = 0.f;
        for (int k2 = 0; k2 < 128; k2++) a2v = fmaf(h1[k2], fc2W[k2 * 64 + t], a2v);
        h2[t] = a2v + fc2b[t];
    }
    __syncthreads();
    // LN2
    red[t] = (t < 64) ? h2[t] : 0.f;
    __syncthreads();
    for (int s = 128; s >= 1; s >>= 1) { if (t < s) red[t] += red[t + s]; __syncthreads(); }
    float mean2 = red[0] / 64.f;
    __syncthreads();
    float dv2 = (t < 64) ? (h2[t] - mean2) : 0.f;
    red[t] = dv2 * dv2;
    __syncthreads();
    for (int s = 128; s >= 1; s >>= 1) { if (t < s) red[t] += red[t + s]; __syncthreads(); }
    float var2 = red[0] / 64.f;
    __syncthreads();
    if (t < 64)
        h2[t] = fmaxf((h2[t] - mean2) * rsqrtf(var2 + 1e-5f) * ln2g[t] + ln2b[t], 0.f);
    __syncthreads();
    // fc3 + sigmoid
    red[t] = (t < 64) ? h2[t] * fc3W[t] : 0.f;
    __syncthreads();
    for (int s = 128; s >= 1; s >>= 1) { if (t < s) red[t] += red[t + s]; __syncthreads(); }
    if (t == 0) out[b] = 1.f / (1.f + expf(-(red[0] + fc3b[0])));
}

// ---------------------------------------------------------------------------
extern "C" void kernel_launch(void* const* d_in, const int* in_sizes, int n_in,
                              void* d_out, int out_size, void* d_ws, size_t ws_size,
                              hipStream_t stream) {
    const float* x1   = (const float*)d_in[0];
    const float* ew1  = (const float*)d_in[1];
    const float* x2   = (const float*)d_in[2];
    const float* ew2  = (const float*)d_in[3];
    const float* Wg1  = (const float*)d_in[4];
    const float* bg1  = (const float*)d_in[5];
    const float* Wg2  = (const float*)d_in[6];
    const float* bg2  = (const float*)d_in[7];
    const float* fc1W = (const float*)d_in[8];
    const float* fc1b = (const float*)d_in[9];
    const float* ln1g = (const float*)d_in[10];
    const float* ln1b = (const float*)d_in[11];
    const float* fc2W = (const float*)d_in[12];
    const float* fc2b = (const float*)d_in[13];
    const float* ln2g = (const float*)d_in[14];
    const float* ln2b = (const float*)d_in[15];
    const float* fc3W = (const float*)d_in[16];
    const float* fc3b = (const float*)d_in[17];
    const int* ei1    = (const int*)d_in[18];
    const int* ei2    = (const int*)d_in[19];
    float* out = (float*)d_out;

    const int N1 = in_sizes[0] / 128;        // 102400
    const int E1 = in_sizes[1];              // 1638400
    const int N2 = in_sizes[2] / 128;        // 199
    const int E2 = in_sizes[3];              // 3184
    const int B  = out_size;                 // 64
    const int NPG = N1 / B;                  // 1600
    const int K  = (in_sizes[8] / 128) / N2; // 50
    const int PK = K * N2;                   // 9950

    // -------- workspace layout --------
    char* wsb = (char*)d_ws;
    size_t o = 0;
    auto alloc = [&](size_t bytes) -> void* {
        void* p = wsb + o;
        o += (bytes + 255) & ~(size_t)255;
        return p;
    };
    float* deg1   = (float*)alloc((size_t)N1 * 4);        // becomes dinv1
    int*   cnt    = (int*)alloc((size_t)N1 * 4);
    int*   cur    = (int*)alloc((size_t)N1 * 4);
    int*   off    = (int*)alloc((size_t)(N1 + 1) * 4);
    int*   csre   = (int*)alloc((size_t)E1 * 4);
    float* z      = (float*)alloc((size_t)N1 * 128 * 4);  // z1, then z2
    float* h      = (float*)alloc((size_t)N1 * 128 * 4);  // h1, then o1
    float* dl     = (float*)alloc((size_t)N1 * 4);
    int*   tki    = (int*)alloc((size_t)B * K * 4);
    float* pooled = (float*)alloc((size_t)B * K * N2 * 4);
    float* dinv2  = (float*)alloc((size_t)N2 * 4);
    float* z2g    = (float*)alloc((size_t)N2 * 128 * 4);
    float* h2b    = (float*)alloc((size_t)N2 * 128 * 4);
    float* a2a    = (float*)alloc((size_t)N2 * 128 * 4);
    float* zz2    = (float*)alloc((size_t)N2 * 64 * 4);
    float* a2b    = (float*)alloc((size_t)N2 * 64 * 4);
    float* o2b    = (float*)alloc((size_t)N2 * 64 * 4);
    float* s2     = (float*)alloc((size_t)N2 * 4);
    (void)ws_size; (void)n_in;

    const int* src1 = ei1;
    const int* dst1 = ei1 + E1;

    // -------- graph1 GNN --------
    init1_kernel<<<(N1 + 255) / 256, 256, 0, stream>>>(deg1, cnt, cur, N1);
    hist_kernel<<<(E1 + 255) / 256, 256, 0, stream>>>(dst1, ew1, deg1, cnt, E1);
    rsqrt_kernel<<<(N1 + 255) / 256, 256, 0, stream>>>(deg1, N1);
    scan_kernel<<<1, 1024, 0, stream>>>(cnt, off, N1);
    csr_kernel<<<(E1 + 255) / 256, 256, 0, stream>>>(dst1, off, cur, csre, E1);

    gemm_kernel<128><<<N1 / 64, 256, 0, stream>>>(x1, Wg1, z, N1);
    agg_kernel<128><<<(N1 + 3) / 4, 256, 0, stream>>>(z, csre, off, src1, ew1, deg1, bg1, h, N1);
    gemm_kernel<64><<<N1 / 64, 256, 0, stream>>>(h, Wg2, z, N1);   // z := z2
    agg_kernel<64><<<(N1 + 3) / 4, 256, 0, stream>>>(z, csre, off, src1, ew1, deg1, bg2, h, N1); // h := o1

    // -------- graph2 GNN --------
    g2_prep<<<1, 256, 0, stream>>>(ei2, ew2, dinv2, a2a, a2b, E2, N2);
    g2_gemm<128><<<N2, 128, 0, stream>>>(x2, Wg1, z2g, N2);
    g2_scatter<128><<<(E2 + 3) / 4, 256, 0, stream>>>(z2g, ei2, ew2, dinv2, a2a, E2);
    g2_fin<128><<<(N2 * 128 + 255) / 256, 256, 0, stream>>>(a2a, z2g, dinv2, bg1, h2b, N2);
    g2_gemm<64><<<N2, 64, 0, stream>>>(h2b, Wg2, zz2, N2);
    g2_scatter<64><<<(E2 + 3) / 4, 256, 0, stream>>>(zz2, ei2, ew2, dinv2, a2b, E2);
    g2_fin<64><<<(N2 * 64 + 255) / 256, 256, 0, stream>>>(a2b, zz2, dinv2, bg2, o2b, N2);

    // -------- cdist (partial) + SortAggregation + head --------
    s2_kernel<<<(N2 + 3) / 4, 256, 0, stream>>>(o2b, s2, N2);
    dlast_kernel<<<(N1 + 3) / 4, 256, 0, stream>>>(h, o2b, s2, dl, N1, N2);
    topk_kernel<<<B, 256, 0, stream>>>(dl, tki, NPG, K);
    pooled_kernel<<<B * K, 256, 0, stream>>>(h, o2b, s2, tki, pooled, NPG, K, N2);
    head_kernel<<<B, 256, 0, stream>>>(pooled, fc1W, fc1b, ln1g, ln1b, fc2W, fc2b,
                                       ln2g, ln2b, fc3W, fc3b, out, PK);
}

// Round 2
// 956.913 us; speedup vs baseline: 2.1563x; 2.1563x over previous
//
#include <hip/hip_runtime.h>
#include <hip/hip_bf16.h>
#include <cstdint>

// ---------------------------------------------------------------------------
// SiameseGNN: GCNx2 on big graph (N1=102400, E1=1.64M) and small graph
// (N2=199), partial cdist, SortAggregation top-50 per graph, MLP head.
// All f32. Key algorithmic save: never materialize the full [N1 x N2] dist
// matrix; only the last column (selection key) + rows of selected nodes.
// R2: fc1 of the head is now a split-K partial GEMM (2496 blocks) instead of
// 64 latency-bound blocks re-reading 5MB each (was 1687us of 2063us).
// ---------------------------------------------------------------------------

#define DEV_INLINE __device__ __forceinline__

// ---------------- init: deg1=1.0 (self loop), cnt=0, cur=0 -----------------
__global__ void init1_kernel(float* deg, int* cnt, int* cur, int n) {
    int i = blockIdx.x * 256 + threadIdx.x;
    if (i < n) { deg[i] = 1.0f; cnt[i] = 0; cur[i] = 0; }
}

// ---------------- histogram: deg += ew, cnt += 1 per dst -------------------
__global__ void hist_kernel(const int* __restrict__ dst, const float* __restrict__ ew,
                            float* deg, int* cnt, int E) {
    int e = blockIdx.x * 256 + threadIdx.x;
    if (e < E) {
        int d = dst[e];
        atomicAdd(&deg[d], ew[e]);
        atomicAdd(&cnt[d], 1);
    }
}

// ---------------- dinv = rsqrt(deg) in place -------------------------------
__global__ void rsqrt_kernel(float* deg, int n) {
    int i = blockIdx.x * 256 + threadIdx.x;
    if (i < n) deg[i] = rsqrtf(deg[i]);
}

// ---------------- exclusive scan of cnt -> off (single block, 1024 thr) ----
__global__ __launch_bounds__(1024) void scan_kernel(const int* __restrict__ cnt,
                                                    int* __restrict__ off, int n) {
    __shared__ int wsum[16], woff[16];
    __shared__ int carry_s, tot_s;
    int t = threadIdx.x, lane = t & 63, wid = t >> 6;
    if (t == 0) carry_s = 0;
    __syncthreads();
    for (int base = 0; base < n; base += 1024) {
        int i = base + t;
        int v = (i < n) ? cnt[i] : 0;
        int s = v;
        for (int d = 1; d < 64; d <<= 1) { int u = __shfl_up(s, d); if (lane >= d) s += u; }
        if (lane == 63) wsum[wid] = s;
        __syncthreads();
        if (t == 0) {
            int run = 0;
            for (int w2 = 0; w2 < 16; w2++) { int u = wsum[w2]; woff[w2] = run; run += u; }
            tot_s = run;
        }
        __syncthreads();
        if (i < n) off[i] = carry_s + woff[wid] + s - v;   // exclusive
        __syncthreads();
        if (t == 0) carry_s += tot_s;
        __syncthreads();
    }
    if (threadIdx.x == 0) off[n] = carry_s;
}

// ---------------- CSR edge placement (order within bucket arbitrary) -------
__global__ void csr_kernel(const int* __restrict__ dst, const int* __restrict__ off,
                           int* cur, int* __restrict__ csre, int E) {
    int e = blockIdx.x * 256 + threadIdx.x;
    if (e < E) {
        int d = dst[e];
        int pos = off[d] + atomicAdd(&cur[d], 1);
        csre[pos] = e;
    }
}

// ---------------- GEMM: [nrows,128] @ [128,NCOL] -> [nrows,NCOL] -----------
template <int NCOL>
__global__ __launch_bounds__(256) void gemm_kernel(const float* __restrict__ x,
                                                   const float* __restrict__ w,
                                                   float* __restrict__ out, int nrows) {
    constexpr int TX = NCOL / 8;       // 16 or 8
    constexpr int TY = 256 / TX;       // 16 or 32
    constexpr int AR = 64 / TY;        // 4 or 2 rows per thread
    __shared__ float ws[64 * NCOL];
    __shared__ float xs[64 * 68];      // pad 64->68 for bank spread
    int t = threadIdx.x;
    size_t r0 = (size_t)blockIdx.x * 64;
    int tx = t % TX, ty = t / TX;
    float acc[AR][8];
#pragma unroll
    for (int i = 0; i < AR; i++)
#pragma unroll
        for (int j = 0; j < 8; j++) acc[i][j] = 0.f;

    for (int half = 0; half < 2; half++) {
        __syncthreads();
        for (int f = t; f < 64 * NCOL / 4; f += 256)
            ((float4*)ws)[f] = ((const float4*)(w + half * 64 * NCOL))[f];
        for (int f = t; f < 64 * 16; f += 256) {
            int row = f >> 4, c4 = f & 15;
            float4 v = *((const float4*)(x + (r0 + row) * 128 + half * 64 + c4 * 4));
            *((float4*)(xs + row * 68 + c4 * 4)) = v;
        }
        __syncthreads();
        for (int k = 0; k < 64; k++) {
            float4 b0 = *((const float4*)(ws + k * NCOL + tx * 8));
            float4 b1 = *((const float4*)(ws + k * NCOL + tx * 8 + 4));
            float bb[8] = {b0.x, b0.y, b0.z, b0.w, b1.x, b1.y, b1.z, b1.w};
#pragma unroll
            for (int i = 0; i < AR; i++) {
                float a = xs[(ty * AR + i) * 68 + k];
#pragma unroll
                for (int j = 0; j < 8; j++) acc[i][j] = fmaf(a, bb[j], acc[i][j]);
            }
        }
    }
#pragma unroll
    for (int i = 0; i < AR; i++) {
        size_t row = r0 + ty * AR + i;
        float4 v0 = {acc[i][0], acc[i][1], acc[i][2], acc[i][3]};
        float4 v1 = {acc[i][4], acc[i][5], acc[i][6], acc[i][7]};
        *((float4*)(out + row * NCOL + tx * 8)) = v0;
        *((float4*)(out + row * NCOL + tx * 8 + 4)) = v1;
    }
}

// ---------------- CSR aggregation: out = relu(Ahat z + b) ------------------
template <int C>
__global__ __launch_bounds__(256) void agg_kernel(const float* __restrict__ z,
                                                  const int* __restrict__ csre,
                                                  const int* __restrict__ off,
                                                  const int* __restrict__ src,
                                                  const float* __restrict__ ew,
                                                  const float* __restrict__ dinv,
                                                  const float* __restrict__ bias,
                                                  float* __restrict__ out, int n) {
    constexpr int CPL = C / 64;   // 2 or 1 channels per lane
    int wid = threadIdx.x >> 6;
    int lane = threadIdx.x & 63;
    int d = blockIdx.x * 4 + wid;
    if (d >= n) return;
    float dv = dinv[d];
    float acc0, acc1 = 0.f;
    if constexpr (CPL == 2) {
        float2 zv = *((const float2*)(z + (size_t)d * C + lane * 2));
        acc0 = dv * zv.x; acc1 = dv * zv.y;
    } else {
        acc0 = dv * z[(size_t)d * C + lane];
    }
    int o0 = off[d], o1e = off[d + 1];
    for (int base = o0; base < o1e; base += 64) {
        int m = min(64, o1e - base);
        int s = 0; float w = 0.f;
        if (lane < m) {
            int e = csre[base + lane];
            s = src[e];
            w = ew[e] * dinv[s];
        }
        for (int j = 0; j < m; j++) {
            int sj = __shfl(s, j);
            float wj = __shfl(w, j);
            if constexpr (CPL == 2) {
                float2 zv = *((const float2*)(z + (size_t)sj * C + lane * 2));
                acc0 = fmaf(wj, zv.x, acc0);
                acc1 = fmaf(wj, zv.y, acc1);
            } else {
                acc0 = fmaf(wj, z[(size_t)sj * C + lane], acc0);
            }
        }
    }
    if constexpr (CPL == 2) {
        int c = lane * 2;
        out[(size_t)d * C + c]     = fmaxf(dv * acc0 + bias[c], 0.f);
        out[(size_t)d * C + c + 1] = fmaxf(dv * acc1 + bias[c + 1], 0.f);
    } else {
        out[(size_t)d * C + lane] = fmaxf(dv * acc0 + bias[lane], 0.f);
    }
}

// ---------------- graph2: deg->dinv + zero the scatter buffers -------------
__global__ void g2_prep(const int* __restrict__ ei2, const float* __restrict__ ew2,
                        float* dinv2, float* a2a, float* a2b, int E2, int N2) {
    __shared__ float degl[256];
    int t = threadIdx.x;
    degl[t] = 1.0f;
    __syncthreads();
    for (int e = t; e < E2; e += 256) atomicAdd(&degl[ei2[E2 + e]], ew2[e]);
    __syncthreads();
    if (t < N2) dinv2[t] = rsqrtf(degl[t]);
    for (int i = t; i < N2 * 128; i += 256) a2a[i] = 0.f;
    for (int i = t; i < N2 * 64; i += 256) a2b[i] = 0.f;
}

// ---------------- graph2 row-GEMM: block per row ---------------------------
template <int NCOL>
__global__ void g2_gemm(const float* __restrict__ x, const float* __restrict__ w,
                        float* __restrict__ z, int N2) {
    __shared__ float xr[128];
    int row = blockIdx.x, t = threadIdx.x;
    for (int k = t; k < 128; k += NCOL) xr[k] = x[row * 128 + k];
    __syncthreads();
    float acc = 0.f;
    for (int k = 0; k < 128; k++) acc = fmaf(xr[k], w[k * NCOL + t], acc);
    z[row * NCOL + t] = acc;
}

// ---------------- graph2 scatter-atomic aggregation ------------------------
template <int C>
__global__ void g2_scatter(const float* __restrict__ z, const int* __restrict__ ei2,
                           const float* __restrict__ ew2, const float* __restrict__ dinv2,
                           float* a2, int E2) {
    constexpr int CPL = C / 64;
    int wid = threadIdx.x >> 6, lane = threadIdx.x & 63;
    int e = blockIdx.x * 4 + wid;
    if (e >= E2) return;
    int s = ei2[e], d = ei2[E2 + e];
    float nm = dinv2[s] * ew2[e] * dinv2[d];
#pragma unroll
    for (int q = 0; q < CPL; q++) {
        int c = lane * CPL + q;
        atomicAdd(&a2[d * C + c], nm * z[s * C + c]);
    }
}

template <int C>
__global__ void g2_fin(const float* __restrict__ a2, const float* __restrict__ z,
                       const float* __restrict__ dinv2, const float* __restrict__ bias,
                       float* __restrict__ out, int N2) {
    int i = blockIdx.x * 256 + threadIdx.x;
    if (i >= N2 * C) return;
    int n = i / C, c = i % C;
    float dv = dinv2[n];
    out[i] = fmaxf(a2[i] + dv * dv * z[i] + bias[c], 0.f);
}

// ---------------- s2[j] = |o2[j]|^2 ----------------------------------------
__global__ void s2_kernel(const float* __restrict__ o2, float* s2, int N2) {
    int wid = threadIdx.x >> 6, lane = threadIdx.x & 63;
    int j = blockIdx.x * 4 + wid;
    if (j >= N2) return;
    float v = o2[j * 64 + lane];
    float ss = v * v;
    for (int d = 32; d >= 1; d >>= 1) ss += __shfl_xor(ss, d);
    if (lane == 0) s2[j] = ss;
}

// ---------------- dlast[i] = dist(o1[i], o2[N2-1]) -------------------------
__global__ void dlast_kernel(const float* __restrict__ o1, const float* __restrict__ o2,
                             const float* __restrict__ s2, float* __restrict__ dlast,
                             int n, int N2) {
    int wid = threadIdx.x >> 6, lane = threadIdx.x & 63;
    int i = blockIdx.x * 4 + wid;
    if (i >= n) return;
    float a = o1[(size_t)i * 64 + lane];
    float b = o2[(size_t)(N2 - 1) * 64 + lane];
    float aa = a * a, ab = a * b;
    for (int d = 32; d >= 1; d >>= 1) { aa += __shfl_xor(aa, d); ab += __shfl_xor(ab, d); }
    if (lane == 0) {
        float d2 = aa + s2[N2 - 1] - 2.f * ab;
        dlast[i] = sqrtf(fmaxf(d2, 0.f) + 1e-12f);
    }
}

// ---------------- top-K per graph (iterative argmax, stable ties) ----------
__global__ __launch_bounds__(256) void topk_kernel(const float* __restrict__ dlast,
                                                   int* __restrict__ topidx,
                                                   int NPG, int K) {
    __shared__ unsigned long long keys[1600];
    __shared__ unsigned long long red[256];
    int g = blockIdx.x, t = threadIdx.x;
    for (int r = t; r < NPG; r += 256) {
        unsigned vb = __float_as_uint(dlast[(size_t)g * NPG + r]);  // dist > 0
        keys[r] = ((unsigned long long)vb << 32) | (unsigned)(NPG - 1 - r);
    }
    __syncthreads();
    for (int it = 0; it < K; it++) {
        unsigned long long m = 0ull;
        for (int r = t; r < NPG; r += 256) { unsigned long long k = keys[r]; if (k > m) m = k; }
        red[t] = m;
        __syncthreads();
        for (int s = 128; s >= 1; s >>= 1) {
            if (t < s) { if (red[t + s] > red[t]) red[t] = red[t + s]; }
            __syncthreads();
        }
        int rbest = NPG - 1 - (int)(red[0] & 0xffffffffull);
        if (t == 0) { topidx[g * K + it] = rbest; keys[rbest] = 0ull; }
        __syncthreads();
    }
}

// ---------------- pooled rows: dist(o1[sel], o2[j]) for j<N2 ---------------
__global__ void pooled_kernel(const float* __restrict__ o1, const float* __restrict__ o2,
                              const float* __restrict__ s2, const int* __restrict__ topidx,
                              float* __restrict__ pooled, int NPG, int K, int N2) {
    __shared__ float o1s[64];
    __shared__ float s1sh;
    int g = blockIdx.x / K, kk = blockIdx.x % K;
    int t = threadIdx.x;
    int r = topidx[g * K + kk];
    size_t node = (size_t)g * NPG + r;
    if (t < 64) o1s[t] = o1[node * 64 + t];
    __syncthreads();
    if (t < 64) {
        float v = o1s[t]; float ss = v * v;
        for (int d = 32; d >= 1; d >>= 1) ss += __shfl_xor(ss, d);
        if (t == 0) s1sh = ss;
    }
    __syncthreads();
    if (t < N2) {
        float dot = 0.f;
#pragma unroll 8
        for (int k2 = 0; k2 < 64; k2++) dot = fmaf(o1s[k2], o2[t * 64 + k2], dot);
        float d2 = s1sh + s2[t] - 2.f * dot;
        pooled[(size_t)blockIdx.x * N2 + t] = sqrtf(fmaxf(d2, 0.f) + 1e-12f);
    }
}

// ---------------- fc1 split-K partial GEMM ---------------------------------
// grid = NCHUNK * B (chunk-major), 256 threads: 128 cols x 2 row-halves.
// Each block: stage 256 p-rows in LDS, coalesced W row reads, partial -> h1p.
#define FC1_CH 256
__global__ __launch_bounds__(256) void fc1_kernel(const float* __restrict__ pooled,
                                                  const float* __restrict__ fc1W,
                                                  float* __restrict__ h1p,
                                                  int PK, int NCHUNK, int B) {
    __shared__ float ps[FC1_CH];
    __shared__ float red[256];
    int b = blockIdx.x % B, ch = blockIdx.x / B;
    int r0 = ch * FC1_CH;
    int nr = min(FC1_CH, PK - r0);
    int t = threadIdx.x;
    for (int i = t; i < nr; i += 256) ps[i] = pooled[(size_t)b * PK + r0 + i];
    __syncthreads();
    int c = t & 127, half = t >> 7;
    int rb = half * (FC1_CH / 2);
    int re = min(rb + FC1_CH / 2, nr);
    float acc = 0.f;
    for (int r = rb; r < re; r++)
        acc = fmaf(ps[r], fc1W[(size_t)(r0 + r) * 128 + c], acc);
    red[t] = acc;
    __syncthreads();
    if (t < 128) h1p[((size_t)b * NCHUNK + ch) * 128 + t] = red[t] + red[t + 128];
}

// ---------------- head tail: reduce partials + LN/fc2/LN/fc3/sigmoid -------
__global__ __launch_bounds__(256) void head2_kernel(
    const float* __restrict__ h1p, int NCHUNK,
    const float* __restrict__ fc1b, const float* __restrict__ ln1g,
    const float* __restrict__ ln1b, const float* __restrict__ fc2W,
    const float* __restrict__ fc2b, const float* __restrict__ ln2g,
    const float* __restrict__ ln2b, const float* __restrict__ fc3W,
    const float* __restrict__ fc3b, float* __restrict__ out) {
    __shared__ float red[256];
    __shared__ float h1[128];
    __shared__ float h2[64];
    int b = blockIdx.x, t = threadIdx.x;
    if (t < 128) {
        float s = 0.f;
        for (int ch = 0; ch < NCHUNK; ch++)
            s += h1p[((size_t)b * NCHUNK + ch) * 128 + t];
        h1[t] = s + fc1b[t];
    }
    __syncthreads();
    // LN1
    red[t] = (t < 128) ? h1[t] : 0.f;
    __syncthreads();
    for (int s = 128; s >= 1; s >>= 1) { if (t < s) red[t] += red[t + s]; __syncthreads(); }
    float mean1 = red[0] / 128.f;
    __syncthreads();
    float dv1 = (t < 128) ? (h1[t] - mean1) : 0.f;
    red[t] = dv1 * dv1;
    __syncthreads();
    for (int s = 128; s >= 1; s >>= 1) { if (t < s) red[t] += red[t + s]; __syncthreads(); }
    float var1 = red[0] / 128.f;
    __syncthreads();
    if (t < 128) {
        float y = (h1[t] - mean1) * rsqrtf(var1 + 1e-5f) * ln1g[t] + ln1b[t];
        h1[t] = fmaxf(y, 0.f);
    }
    __syncthreads();
    // fc2
    if (t < 64) {
        float a2v = 0.f;
        for (int k2 = 0; k2 < 128; k2++) a2v = fmaf(h1[k2], fc2W[k2 * 64 + t], a2v);
        h2[t] = a2v + fc2b[t];
    }
    __syncthreads();
    // LN2
    red[t] = (t < 64) ? h2[t] : 0.f;
    __syncthreads();
    for (int s = 128; s >= 1; s >>= 1) { if (t < s) red[t] += red[t + s]; __syncthreads(); }
    float mean2 = red[0] / 64.f;
    __syncthreads();
    float dv2 = (t < 64) ? (h2[t] - mean2) : 0.f;
    red[t] = dv2 * dv2;
    __syncthreads();
    for (int s = 128; s >= 1; s >>= 1) { if (t < s) red[t] += red[t + s]; __syncthreads(); }
    float var2 = red[0] / 64.f;
    __syncthreads();
    if (t < 64)
        h2[t] = fmaxf((h2[t] - mean2) * rsqrtf(var2 + 1e-5f) * ln2g[t] + ln2b[t], 0.f);
    __syncthreads();
    // fc3 + sigmoid
    red[t] = (t < 64) ? h2[t] * fc3W[t] : 0.f;
    __syncthreads();
    for (int s = 128; s >= 1; s >>= 1) { if (t < s) red[t] += red[t + s]; __syncthreads(); }
    if (t == 0) out[b] = 1.f / (1.f + expf(-(red[0] + fc3b[0])));
}

// ---------------------------------------------------------------------------
extern "C" void kernel_launch(void* const* d_in, const int* in_sizes, int n_in,
                              void* d_out, int out_size, void* d_ws, size_t ws_size,
                              hipStream_t stream) {
    const float* x1   = (const float*)d_in[0];
    const float* ew1  = (const float*)d_in[1];
    const float* x2   = (const float*)d_in[2];
    const float* ew2  = (const float*)d_in[3];
    const float* Wg1  = (const float*)d_in[4];
    const float* bg1  = (const float*)d_in[5];
    const float* Wg2  = (const float*)d_in[6];
    const float* bg2  = (const float*)d_in[7];
    const float* fc1W = (const float*)d_in[8];
    const float* fc1b = (const float*)d_in[9];
    const float* ln1g = (const float*)d_in[10];
    const float* ln1b = (const float*)d_in[11];
    const float* fc2W = (const float*)d_in[12];
    const float* fc2b = (const float*)d_in[13];
    const float* ln2g = (const float*)d_in[14];
    const float* ln2b = (const float*)d_in[15];
    const float* fc3W = (const float*)d_in[16];
    const float* fc3b = (const float*)d_in[17];
    const int* ei1    = (const int*)d_in[18];
    const int* ei2    = (const int*)d_in[19];
    float* out = (float*)d_out;

    const int N1 = in_sizes[0] / 128;        // 102400
    const int E1 = in_sizes[1];              // 1638400
    const int N2 = in_sizes[2] / 128;        // 199
    const int E2 = in_sizes[3];              // 3184
    const int B  = out_size;                 // 64
    const int NPG = N1 / B;                  // 1600
    const int K  = (in_sizes[8] / 128) / N2; // 50
    const int PK = K * N2;                   // 9950
    const int NCHUNK = (PK + FC1_CH - 1) / FC1_CH;  // 39

    // -------- workspace layout --------
    char* wsb = (char*)d_ws;
    size_t o = 0;
    auto alloc = [&](size_t bytes) -> void* {
        void* p = wsb + o;
        o += (bytes + 255) & ~(size_t)255;
        return p;
    };
    float* deg1   = (float*)alloc((size_t)N1 * 4);        // becomes dinv1
    int*   cnt    = (int*)alloc((size_t)N1 * 4);
    int*   cur    = (int*)alloc((size_t)N1 * 4);
    int*   off    = (int*)alloc((size_t)(N1 + 1) * 4);
    int*   csre   = (int*)alloc((size_t)E1 * 4);
    float* z      = (float*)alloc((size_t)N1 * 128 * 4);  // z1, then z2
    float* h      = (float*)alloc((size_t)N1 * 128 * 4);  // h1, then o1
    float* dl     = (float*)alloc((size_t)N1 * 4);
    int*   tki    = (int*)alloc((size_t)B * K * 4);
    float* pooled = (float*)alloc((size_t)B * K * N2 * 4);
    float* h1p    = (float*)alloc((size_t)B * NCHUNK * 128 * 4);
    float* dinv2  = (float*)alloc((size_t)N2 * 4);
    float* z2g    = (float*)alloc((size_t)N2 * 128 * 4);
    float* h2b    = (float*)alloc((size_t)N2 * 128 * 4);
    float* a2a    = (float*)alloc((size_t)N2 * 128 * 4);
    float* zz2    = (float*)alloc((size_t)N2 * 64 * 4);
    float* a2b    = (float*)alloc((size_t)N2 * 64 * 4);
    float* o2b    = (float*)alloc((size_t)N2 * 64 * 4);
    float* s2     = (float*)alloc((size_t)N2 * 4);
    (void)ws_size; (void)n_in;

    const int* src1 = ei1;
    const int* dst1 = ei1 + E1;

    // -------- graph1 GNN --------
    init1_kernel<<<(N1 + 255) / 256, 256, 0, stream>>>(deg1, cnt, cur, N1);
    hist_kernel<<<(E1 + 255) / 256, 256, 0, stream>>>(dst1, ew1, deg1, cnt, E1);
    rsqrt_kernel<<<(N1 + 255) / 256, 256, 0, stream>>>(deg1, N1);
    scan_kernel<<<1, 1024, 0, stream>>>(cnt, off, N1);
    csr_kernel<<<(E1 + 255) / 256, 256, 0, stream>>>(dst1, off, cur, csre, E1);

    gemm_kernel<128><<<N1 / 64, 256, 0, stream>>>(x1, Wg1, z, N1);
    agg_kernel<128><<<(N1 + 3) / 4, 256, 0, stream>>>(z, csre, off, src1, ew1, deg1, bg1, h, N1);
    gemm_kernel<64><<<N1 / 64, 256, 0, stream>>>(h, Wg2, z, N1);   // z := z2
    agg_kernel<64><<<(N1 + 3) / 4, 256, 0, stream>>>(z, csre, off, src1, ew1, deg1, bg2, h, N1); // h := o1

    // -------- graph2 GNN --------
    g2_prep<<<1, 256, 0, stream>>>(ei2, ew2, dinv2, a2a, a2b, E2, N2);
    g2_gemm<128><<<N2, 128, 0, stream>>>(x2, Wg1, z2g, N2);
    g2_scatter<128><<<(E2 + 3) / 4, 256, 0, stream>>>(z2g, ei2, ew2, dinv2, a2a, E2);
    g2_fin<128><<<(N2 * 128 + 255) / 256, 256, 0, stream>>>(a2a, z2g, dinv2, bg1, h2b, N2);
    g2_gemm<64><<<N2, 64, 0, stream>>>(h2b, Wg2, zz2, N2);
    g2_scatter<64><<<(E2 + 3) / 4, 256, 0, stream>>>(zz2, ei2, ew2, dinv2, a2b, E2);
    g2_fin<64><<<(N2 * 64 + 255) / 256, 256, 0, stream>>>(a2b, zz2, dinv2, bg2, o2b, N2);

    // -------- cdist (partial) + SortAggregation + head --------
    s2_kernel<<<(N2 + 3) / 4, 256, 0, stream>>>(o2b, s2, N2);
    dlast_kernel<<<(N1 + 3) / 4, 256, 0, stream>>>(h, o2b, s2, dl, N1, N2);
    topk_kernel<<<B, 256, 0, stream>>>(dl, tki, NPG, K);
    pooled_kernel<<<B * K, 256, 0, stream>>>(h, o2b, s2, tki, pooled, NPG, K, N2);
    fc1_kernel<<<NCHUNK * B, 256, 0, stream>>>(pooled, fc1W, h1p, PK, NCHUNK, B);
    head2_kernel<<<B, 256, 0, stream>>>(h1p, NCHUNK, fc1b, ln1g, ln1b, fc2W, fc2b,
                                        ln2g, ln2b, fc3W, fc3b, out);
}